// Round 14
// baseline (41.529 us; speedup 1.0000x reference)
//
#include <hip/hip_runtime.h>
#include <hip/hip_bf16.h>
#include <stdint.h>

// KANLinear: y[b,o] = sum_{d,k} coeff[b,d,k]*values[o,d,k] + xc@skip_w^T + skip_b
//   Vp[o,d*16+k] = values[o,d,k] + grid[k]*skip_w[o,d]   (prep, bf16)
//   y = A @ Vp^T + skip_b  (MFMA GEMM  M=8192 N=256 K=4096)
// Round 14: T3/T4 per-wave self-synced DMA pipeline. Each wave DMAs ONLY the
//   B-slice it reads (8 global_load_lds/iter, linear dest) and orders it with
//   counted s_waitcnt vmcnt(8) - never drained, no cross-wave B sync needed.
//   A via LDS dbuf + 1 lgkm barrier/iter. BM=64 BN=256 (no B dup), 4 waves
//   1x4, KS=4, grid 512 = 2 blocks/CU, LDS 80KB/block. x preloaded to regs
//   (exact vmcnt counting); K-loop fully unrolled (static reg indexing).

#define D_DIM  256
#define O_DIM  256
#define BM     64
#define BK     64
#define KS     4
#define ITERS  16             // (4096/KS)/BK
#define NTHR   256

typedef __attribute__((ext_vector_type(8))) short bf16x8;
typedef __attribute__((ext_vector_type(4))) float f32x4;

// ---------------------------------------------------------------------------
// Prep (proven R6-R13): Vp chunk-transposed: chunk c = kflat>>3 (16B of 8
// bf16) stored at Vp[(c*256 + o)*8] -> 1KB-coalesced per 64-lane DMA.
// ---------------------------------------------------------------------------
__global__ __launch_bounds__(256) void kan_prep(
    const float* __restrict__ values,   // [O][D][K]
    const float* __restrict__ skip_w,   // [O][D]
    const float* __restrict__ gknots,   // [K]
    unsigned short* __restrict__ Vp)    // 2 MB bf16, chunk-transposed
{
    int tid = blockIdx.x * blockDim.x + threadIdx.x;    // 0..131071
    int e = tid * 8;
    int o = e >> 12;
    int kflat = e & 4095;
    float sw = skip_w[(o << 8) | (kflat >> 4)];
    int kmod = kflat & 15;                              // 0 or 8

    const float4* vp4 = reinterpret_cast<const float4*>(values + e);
    float4 v0 = vp4[0], v1 = vp4[1];
    float f[8] = {v0.x, v0.y, v0.z, v0.w, v1.x, v1.y, v1.z, v1.w};
    unsigned int w[4];
#pragma unroll
    for (int j = 0; j < 4; ++j) {
        float2 ab;
        ab.x = f[2*j]     + gknots[kmod + 2*j]     * sw;
        ab.y = f[2*j + 1] + gknots[kmod + 2*j + 1] * sw;
        __hip_bfloat162 p2 = __float22bfloat162_rn(ab);
        __builtin_memcpy(&w[j], &p2, 4);
    }
    size_t c = (size_t)(kflat >> 3) * 256 + (size_t)o;
    *reinterpret_cast<uint4*>(Vp + c * 8) = make_uint4(w[0], w[1], w[2], w[3]);
}

// ---------------------------------------------------------------------------
// GEMM: BM=64 x BN=256 x BK=64; 4 waves, wave w owns cols w*64..w*64+63
// (wave-tile 64x64, acc[4][4]). B: per-wave DMA into Bs[buf][chunk][n],
// counted vmcnt. A: LDS dbuf, XOR swizzle, 1 barrier/iter. KS=4 partials.
// ---------------------------------------------------------------------------
__global__ __launch_bounds__(NTHR, 2) void kan_gemm(
    const float* __restrict__ x,          // [B][D] f32
    const unsigned short* __restrict__ Vp,
    float* __restrict__ part,             // [3][8192][256] f32 (ks=1..3)
    float* __restrict__ out)              // [8192][256] f32 (ks=0 partial)
{
    __shared__ unsigned short As[2][BM * BK];       // 2 x 8 KB
    __shared__ unsigned short Bs[2][8 * 256 * 8];   // 2 x 32 KB

    const int t    = threadIdx.x;
    const int lane = t & 63;
    const int wid  = t >> 6;           // wave = col slice wid*64
    const int l15  = lane & 15;
    const int lhi  = lane >> 4;        // 0..3
    const int wn64 = wid * 64;

    const int bid = (int)blockIdx.x;
    const int m8  = bid & 7;                        // == XCD
    const int ks  = (bid >> 3) & 3;
    const int mhi = bid >> 5;                       // 0..15
    const int mt  = m8 + 8 * mhi;                   // 0..127, mt%8==XCD
    const int bm0 = mt * BM;
    const size_t kc0 = (size_t)ks * 128;            // global 16B-chunk base

    // ---- x preload: one value per thread per iter (16 regs)
    const int ar = t >> 2;             // row 0..63
    const int dg = t & 3;
    const float* xp = x + (size_t)(bm0 + ar) * D_DIM + ks * 64 + dg;
    float xs[ITERS];
#pragma unroll
    for (int j = 0; j < ITERS; ++j) xs[j] = xp[j * 4];

    char* arow[2] = { (char*)&As[0][0] + ar * 128, (char*)&As[1][0] + ar * 128 };
    const int ca = ((2 * dg)     ^ (ar & 7)) * 16;
    const int cb = ((2 * dg + 1) ^ (ar & 7)) * 16;

    auto stageA = [&](int buf, float xv) {
        float xc = fminf(1.f, fmaxf(-1.f, xv));
        float tt = (xc + 1.f) * 7.5f;            // (xc - g0)/h, h = 2/15
        int li = (int)tt;
        li = li > 14 ? 14 : li;
        float w1 = tt - (float)li;
        float2 cw; cw.x = 1.f - w1; cw.y = w1;
        __hip_bfloat162 p2 = __float22bfloat162_rn(cw);   // v_cvt_pk_bf16_f32
        unsigned int pk;
        __builtin_memcpy(&pk, &p2, 4);
        unsigned long long w64 = (unsigned long long)pk << ((li & 1) * 16);
        unsigned int lo = (unsigned int)w64;
        unsigned int hi = (unsigned int)(w64 >> 32);
        int jl = li >> 1;
        unsigned int wd[8];
#pragma unroll
        for (int j = 0; j < 8; ++j)
            wd[j] = (j == jl) ? lo : ((j == jl + 1) ? hi : 0u);
        char* a = arow[buf];
        *reinterpret_cast<uint4*>(a + ca) = make_uint4(wd[0], wd[1], wd[2], wd[3]);
        *reinterpret_cast<uint4*>(a + cb) = make_uint4(wd[4], wd[5], wd[6], wd[7]);
    };

    // per-wave B DMA: 8 insts, chunk j -> Bs[buf][j][wn64 + lane]
    #define DMAB(BUF, KT)                                                      \
        {                                                                      \
            const unsigned short* _src = Vp + (kc0 + (size_t)(KT) * 8) * 2048; \
            char* _lb = (char*)&Bs[BUF][0];                                    \
            _Pragma("unroll")                                                  \
            for (int j = 0; j < 8; ++j) {                                      \
                const char* g = (const char*)(_src + (size_t)j * 2048)         \
                                + (wn64 + lane) * 16;                          \
                unsigned ldsoff = (unsigned)((j * 256 + wn64) * 16);           \
                __builtin_amdgcn_global_load_lds(                              \
                    (const __attribute__((address_space(1))) unsigned int*)g,  \
                    (__attribute__((address_space(3))) unsigned int*)          \
                        (_lb + ldsoff),                                        \
                    16, 0, 0);                                                 \
            }                                                                  \
        }

    // per-thread A-read constants
    int abyte[4], a7[4];
#pragma unroll
    for (int mi = 0; mi < 4; ++mi) {
        int m = mi * 16 + l15;
        abyte[mi] = m * 128;
        a7[mi] = m & 7;
    }
    // B-read byte offsets (chunk = kh*4+lhi, n = wn64 + ni*16 + l15)
    int bbyte[2][4];
#pragma unroll
    for (int kh = 0; kh < 2; ++kh)
#pragma unroll
        for (int ni = 0; ni < 4; ++ni)
            bbyte[kh][ni] = (((kh * 4 + lhi) * 256) + wn64 + ni * 16 + l15) * 16;

    f32x4 acc[4][4] = {};

    // ---- prologue: DMA(0), stage A(0), full drain once
    DMAB(0, 0)
    stageA(0, xs[0]);
    asm volatile("s_waitcnt vmcnt(0) lgkmcnt(0)" ::: "memory");
    __builtin_amdgcn_s_barrier();
    __builtin_amdgcn_sched_barrier(0);

    #define IT(KT, CUR)                                                        \
        {                                                                      \
            if ((KT) + 1 < ITERS) {                                            \
                DMAB((CUR) ^ 1, (KT) + 1)                                      \
                asm volatile("s_waitcnt vmcnt(8)" ::: "memory");               \
            } else {                                                           \
                asm volatile("s_waitcnt vmcnt(0)" ::: "memory");               \
            }                                                                  \
            __builtin_amdgcn_sched_barrier(0);                                 \
            const char* Ab = (const char*)&As[CUR][0];                         \
            const char* Bb = (const char*)&Bs[CUR][0];                         \
            bf16x8 af[4][2], bg[4][2];                                         \
            _Pragma("unroll")                                                  \
            for (int kh = 0; kh < 2; ++kh) {                                   \
                int k8 = kh * 4 + lhi;                                         \
                _Pragma("unroll")                                              \
                for (int mi = 0; mi < 4; ++mi)                                 \
                    af[mi][kh] = *reinterpret_cast<const bf16x8*>(             \
                        Ab + abyte[mi] + ((k8 ^ a7[mi]) << 4));                \
                _Pragma("unroll")                                              \
                for (int ni = 0; ni < 4; ++ni)                                 \
                    bg[ni][kh] = *reinterpret_cast<const bf16x8*>(             \
                        Bb + bbyte[kh][ni]);                                   \
            }                                                                  \
            if ((KT) + 1 < ITERS) stageA((CUR) ^ 1, xs[(KT) + 1 < ITERS ?     \
                                                       (KT) + 1 : 0]);         \
            __builtin_amdgcn_s_setprio(1);                                     \
            _Pragma("unroll")                                                  \
            for (int mi = 0; mi < 4; ++mi)                                     \
                _Pragma("unroll")                                              \
                for (int ni = 0; ni < 4; ++ni)                                 \
                    _Pragma("unroll")                                          \
                    for (int kh = 0; kh < 2; ++kh)                             \
                        acc[mi][ni] = __builtin_amdgcn_mfma_f32_16x16x32_bf16( \
                            af[mi][kh], bg[ni][kh], acc[mi][ni], 0, 0, 0);     \
            __builtin_amdgcn_s_setprio(0);                                     \
            if ((KT) + 1 < ITERS) {                                            \
                asm volatile("s_waitcnt lgkmcnt(0)" ::: "memory");             \
                __builtin_amdgcn_s_barrier();                                  \
                __builtin_amdgcn_sched_barrier(0);                             \
            }                                                                  \
        }

    IT(0, 0)   IT(1, 1)   IT(2, 0)   IT(3, 1)
    IT(4, 0)   IT(5, 1)   IT(6, 0)   IT(7, 1)
    IT(8, 0)   IT(9, 1)   IT(10, 0)  IT(11, 1)
    IT(12, 0)  IT(13, 1)  IT(14, 0)  IT(15, 1)
    #undef IT
    #undef DMAB

    // ---- epilogue: raw partial store (bias added in reduce)
    float* dst = (ks == 0) ? out : part + (size_t)(ks - 1) * (8192 * 256);
#pragma unroll
    for (int ni = 0; ni < 4; ++ni) {
        int col = wn64 + ni * 16 + l15;
#pragma unroll
        for (int mi = 0; mi < 4; ++mi) {
            f32x4 v = acc[mi][ni];
            int row0 = bm0 + mi * 16 + lhi * 4;
#pragma unroll
            for (int r = 0; r < 4; ++r)
                dst[(size_t)(row0 + r) * O_DIM + col] = v[r];
        }
    }
}

// ---------------------------------------------------------------------------
// Reduce (R13): out += part[0..2] + skip_b, XCD-congruent mapping.
// ---------------------------------------------------------------------------
__global__ __launch_bounds__(256) void kan_reduce(
    const float* __restrict__ part,   // [3][8192][256]
    const float* __restrict__ skip_b, // [256]
    float* __restrict__ out)          // [8192][256] (holds ks=0 partial)
{
    int rbid = (int)blockIdx.x;       // 0..2047
    int c    = rbid & 7;
    int tq   = rbid >> 3;             // 0..255
    int mhi  = tq >> 4;               // 0..15
    int sub  = tq & 15;               // 0..15 -> 4-row stripe within mt
    int mt   = c + 8 * mhi;           // 0..127
    int row0 = mt * BM + sub * 4;

    int i   = (int)threadIdx.x;
    int row = row0 + (i >> 6);
    int col = (i & 63) * 4;
    size_t e = (size_t)row * O_DIM + col;

    f32x4 s = *reinterpret_cast<const f32x4*>(out + e);
    s += *reinterpret_cast<const f32x4*>(skip_b + col);
    s += *reinterpret_cast<const f32x4*>(part + e);
    s += *reinterpret_cast<const f32x4*>(part + (size_t)8192 * 256 + e);
    s += *reinterpret_cast<const f32x4*>(part + (size_t)2 * 8192 * 256 + e);
    *reinterpret_cast<f32x4*>(out + e) = s;
}

// ---------------------------------------------------------------------------
// Naive fallback (tiny workspace only) — correct, slow.
// ---------------------------------------------------------------------------
__global__ __launch_bounds__(256) void kan_naive(
    const float* __restrict__ x,
    const unsigned short* __restrict__ Vp,   // chunk-transposed
    const float* __restrict__ skip_b,
    float* __restrict__ out)
{
    int b = blockIdx.x, o = threadIdx.x;
    float acc = skip_b[o];
    for (int d = 0; d < 256; ++d) {
        float xc = fminf(1.f, fmaxf(-1.f, x[(size_t)b * 256 + d]));
        float tt = (xc + 1.f) * 7.5f;
        int li = (int)tt; li = li > 14 ? 14 : li;
        float w1 = tt - (float)li;
        int k0 = d * 16 + li;
        unsigned short u0 = Vp[((size_t)(k0 >> 3) * 256 + o) * 8 + (k0 & 7)];
        int k1 = k0 + 1;
        unsigned short u1 = Vp[((size_t)(k1 >> 3) * 256 + o) * 8 + (k1 & 7)];
        float f0 = __uint_as_float((unsigned)u0 << 16);
        float f1 = __uint_as_float((unsigned)u1 << 16);
        acc += (1.f - w1) * f0 + w1 * f1;
    }
    out[(size_t)b * 256 + o] = acc;
}

extern "C" void kernel_launch(void* const* d_in, const int* in_sizes, int n_in,
                              void* d_out, int out_size, void* d_ws, size_t ws_size,
                              hipStream_t stream) {
    const float* x      = (const float*)d_in[0];   // [8192][256]
    const float* values = (const float*)d_in[1];   // [256][256][16]
    const float* skip_w = (const float*)d_in[2];   // [256][256]
    const float* skip_b = (const float*)d_in[3];   // [256]
    const float* gknots = (const float*)d_in[4];   // [16]
    float* out = (float*)d_out;
    (void)in_sizes; (void)n_in; (void)out_size;

    unsigned short* Vp = (unsigned short*)d_ws;                          // 2 MB
    float* part = (float*)((char*)d_ws + 2u * 1024 * 1024);              // 24 MB

    kan_prep<<<dim3(512), dim3(256), 0, stream>>>(values, skip_w, gknots, Vp);

    const size_t need = 2u * 1024 * 1024
                      + (size_t)3 * 8192 * 256 * sizeof(float);
    if (ws_size >= need) {
        // 128 mt x 4 ks = 512 blocks = 2/CU, XCD-coherent (mt%8 == bid%8)
        kan_gemm<<<dim3(512), dim3(NTHR), 0, stream>>>(x, Vp, part, out);
        kan_reduce<<<dim3(2048), dim3(256), 0, stream>>>(part, skip_b, out);
    } else {
        kan_naive<<<dim3(8192), dim3(256), 0, stream>>>(x, Vp, skip_b, out);
    }
}